// Round 7
// baseline (574.965 us; speedup 1.0000x reference)
//
#include <hip/hip_runtime.h>
#include <hip/hip_bf16.h>
#include <math.h>

// ---------------------------------------------------------------------------
// Mamba2 forward, MI355X. Round 7: consolidation.
//   P  prep_kernel   : cast(u) + transpose(W_in) + transpose(W_out*norm_w)
//                      + colsum(t1,t2) in one sectioned dispatch
//   K1 gemm_bt<DT>   : zxbcdt = u @ W_in, dt=softplus folded into epilogue
//   K3 conv_silu     : ushort4-vectorized, 8 rows x 4 cols per thread
//   K4 chunk_state   : MFMA per (b,chunk,head)
//   K5 scan          : sequential inter-chunk scan with software prefetch
//   K6 y_kernel      : 4 heads/block; G once; Yoff B-frags direct from global;
//                      emits LN partial sums
//   K8 gemm_bt<FOLD> : out = LN(y) @ W_out; mu/rstd derived in prologue
// ---------------------------------------------------------------------------

namespace {

constexpr int kB   = 2;
constexpr int kL   = 4096;
constexpr int kDI  = 2048;
constexpr int kDS  = 128;
constexpr int kNH  = 32;
constexpr int kHP  = 64;
constexpr int kDC  = 4;
constexpr int kCS  = 64;
constexpr int kNC  = kL / kCS;
constexpr int kDProj   = 2 * kDI + 2 * kDS + kNH;  // 4384
constexpr int kDProjP  = 4480;                     // 35*128
constexpr int kConvDim = kDI + 2 * kDS;            // 2304
constexpr int kRows = kB * kL;                     // 8192
constexpr float kEps = 1e-5f;
constexpr int kTS = 136;   // LDS stride for [64][128] tiles
constexpr int kWS = 72;    // LDS stride for [64][64] tiles

typedef __bf16 bf16x8 __attribute__((ext_vector_type(8)));
typedef float f32x4 __attribute__((ext_vector_type(4)));
typedef unsigned short ushort8 __attribute__((ext_vector_type(8)));

__device__ inline float bu2f(unsigned short u) {
  union { unsigned int i; float f; } x; x.i = ((unsigned int)u) << 16; return x.f;
}
__device__ inline unsigned short f2bu(float f) {
  __hip_bfloat16 h = __float2bfloat16(f);
  return *reinterpret_cast<unsigned short*>(&h);
}

__device__ inline void store_out(float* C, size_t i, float v) { C[i] = v; }
__device__ inline void store_out(unsigned short* C, size_t i, float v) { C[i] = f2bu(v); }

__device__ inline void gld_lds16(const unsigned short* g, unsigned short* l) {
  __builtin_amdgcn_global_load_lds(
      (const __attribute__((address_space(1))) unsigned int*)g,
      (__attribute__((address_space(3))) unsigned int*)l, 16, 0, 0);
}

// ---- P: sectioned prep kernel ------------------------------------------------
__device__ void do_transpose(const float* __restrict__ in, unsigned short* __restrict__ out,
                             int R, int C, const float* __restrict__ scale,
                             int bx, int by, int tid, float (*t)[33]) {
  const int c0 = bx * 32;
  const int r0 = by * 32;
  const int tx = tid & 31, ty = tid >> 5;
  for (int rr = ty; rr < 32; rr += 8) {
    int c = c0 + tx;
    float v = (c < C) ? in[(size_t)(r0 + rr) * C + c] : 0.f;
    if (scale) v *= scale[r0 + rr];
    t[rr][tx] = v;
  }
  __syncthreads();
  for (int cc = ty; cc < 32; cc += 8) {
    int orow = c0 + cc;
    out[(size_t)orow * R + r0 + tx] = f2bu(t[tx][cc]);
  }
}

__global__ void prep_kernel(const float* __restrict__ u, unsigned short* __restrict__ A1,
                            const float* __restrict__ W_in, unsigned short* __restrict__ Bt1,
                            const float* __restrict__ W_out, unsigned short* __restrict__ Bt2,
                            const float* __restrict__ norm_w, const float* __restrict__ norm_b,
                            float* __restrict__ t1, float* __restrict__ t2) {
  __shared__ __align__(16) char smem[32 * 33 * 4];
  int blk = blockIdx.x;
  const int tid = threadIdx.x;
  if (blk < 8192) {                       // cast u -> bf16 (ushort4/thread)
    int i = blk * 256 + tid;
    float4 v = ((const float4*)u)[i];
    ushort4 o;
    o.x = f2bu(v.x); o.y = f2bu(v.y); o.z = f2bu(v.z); o.w = f2bu(v.w);
    ((ushort4*)A1)[i] = o;
    return;
  }
  blk -= 8192;
  if (blk < 140 * 32) {                   // W_in [1024][4384] -> Bt1 [4480][1024]
    do_transpose(W_in, Bt1, 1024, kDProj, nullptr, blk % 140, blk / 140, tid,
                 (float(*)[33])smem);
    return;
  }
  blk -= 140 * 32;
  if (blk < 32 * 64) {                    // W_out [2048][1024] -> Bt2 [1024][2048], *norm_w
    do_transpose(W_out, Bt2, 2048, 1024, norm_w, blk % 32, blk / 32, tid,
                 (float(*)[33])smem);
    return;
  }
  blk -= 32 * 64;                         // colsum: 16 blocks
  {
    float* p1 = (float*)smem;             // [4][64]
    float* p2 = p1 + 256;
    const int nl = tid & 63;
    const int ks = tid >> 6;
    const int n = blk * 64 + nl;
    float s1 = 0.f, s2 = 0.f;
    for (int k = ks * 512; k < ks * 512 + 512; k++) {
      float v = W_out[(size_t)k * 1024 + n];
      s1 += norm_w[k] * v;
      s2 += norm_b[k] * v;
    }
    p1[ks * 64 + nl] = s1; p2[ks * 64 + nl] = s2;
    __syncthreads();
    if (tid < 64) {
      t1[blk * 64 + tid] = p1[tid] + p1[64 + tid] + p1[128 + tid] + p1[192 + tid];
      t2[blk * 64 + tid] = p2[tid] + p2[64 + tid] + p2[128 + tid] + p2[192 + tid];
    }
  }
}

// ---- MFMA GEMM, XOR-swizzled LDS. DT: fold softplus-dt; FOLD: fold LayerNorm.
template <typename OutT, bool FOLD, bool DT>
__global__ __launch_bounds__(256) void gemm_bt(const unsigned short* __restrict__ A,
                                               const unsigned short* __restrict__ Bt,
                                               OutT* __restrict__ C, int M, int N, int K,
                                               const float* __restrict__ pS,
                                               const float* __restrict__ pQ,
                                               const float* __restrict__ t1,
                                               const float* __restrict__ t2,
                                               const float* __restrict__ dt_bias,
                                               float* __restrict__ dtbuf) {
  __shared__ __align__(16) unsigned short As[128 * 32];
  __shared__ __align__(16) unsigned short Bs[128 * 32];
  __shared__ float smu[128], srstd[128];
  const int tid = threadIdx.x;
  const int wave = tid >> 6, lane = tid & 63;
  const int m0 = blockIdx.y * 128, n0 = blockIdx.x * 128;
  if (FOLD && tid < 128) {                // LN stats for this block's 128 rows
    int row = m0 + tid;
    float s = 0.f, q = 0.f;
#pragma unroll
    for (int i = 0; i < 8; i++) { s += pS[(size_t)row * 8 + i]; q += pQ[(size_t)row * 8 + i]; }
    float m = s / kDI;
    smu[tid] = m;
    srstd[tid] = rsqrtf(q / kDI - m * m + kEps);
  }
  const int wr = (wave >> 1) * 64, wc = (wave & 1) * 64;
  const int st_row = lane >> 2;
  const int st_col = (((lane & 3) ^ ((st_row >> 1) & 3))) * 8;  // XOR swizzle
  const unsigned short* pA[2];
  const unsigned short* pB[2];
  unsigned short* lA[2];
  unsigned short* lB[2];
#pragma unroll
  for (int r = 0; r < 2; r++) {
    int q = wave * 2 + r;
    pA[r] = A + (size_t)(m0 + q * 16 + st_row) * K + st_col;
    pB[r] = Bt + (size_t)(n0 + q * 16 + st_row) * K + st_col;
    lA[r] = &As[q * 512];
    lB[r] = &Bs[q * 512];
  }
  const int frag_row = lane & 15;
  const int rk = (((lane >> 4) ^ ((frag_row >> 1) & 3))) * 8;
  f32x4 acc[4][4] = {};
  for (int k0 = 0; k0 < K; k0 += 32) {
#pragma unroll
    for (int r = 0; r < 2; r++) {
      gld_lds16(pA[r] + k0, lA[r]);
      gld_lds16(pB[r] + k0, lB[r]);
    }
    asm volatile("s_waitcnt vmcnt(0)" ::: "memory");
    __syncthreads();
    bf16x8 af[4], bfr[4];
#pragma unroll
    for (int i = 0; i < 4; i++)
      af[i] = *(const bf16x8*)&As[(wr + i * 16 + frag_row) * 32 + rk];
#pragma unroll
    for (int j = 0; j < 4; j++)
      bfr[j] = *(const bf16x8*)&Bs[(wc + j * 16 + frag_row) * 32 + rk];
#pragma unroll
    for (int i = 0; i < 4; i++)
#pragma unroll
      for (int j = 0; j < 4; j++)
        acc[i][j] = __builtin_amdgcn_mfma_f32_16x16x32_bf16(af[i], bfr[j], acc[i][j], 0, 0, 0);
    __syncthreads();
  }
  const int crow = (lane >> 4) * 4;
  const int ccol = lane & 15;
#pragma unroll
  for (int i = 0; i < 4; i++) {
#pragma unroll
    for (int j = 0; j < 4; j++) {
      int n = n0 + wc + j * 16 + ccol;
      if (n < N) {
        float c1 = FOLD ? t1[n] : 0.f;
        float c2 = FOLD ? t2[n] : 0.f;
        bool isdt = DT && (n >= N - kNH);
        float db = isdt ? dt_bias[n - (N - kNH)] : 0.f;
#pragma unroll
        for (int r = 0; r < 4; r++) {
          int m = m0 + wr + i * 16 + crow + r;
          float v = acc[i][j][r];
          if (FOLD) v = srstd[m - m0] * (v - smu[m - m0] * c1) + c2;
          store_out(C, (size_t)m * N + n, v);
          if (isdt) {
            float x = acc[i][j][r] + db;
            dtbuf[(size_t)m * kNH + (n - (N - kNH))] = (x > 15.f) ? x : log1pf(expf(x));
          }
        }
      }
    }
  }
}

// ---- K3: causal depthwise conv (k=4) + SiLU, 8 rows x 4 cols per thread
__global__ void conv_silu_kernel(const unsigned short* __restrict__ zxbcdt,
                                 const float* __restrict__ conv_w,
                                 const float* __restrict__ conv_b,
                                 unsigned short* __restrict__ xbc_act) {
  int c4 = blockIdx.x * 256 + threadIdx.x;
  if (c4 >= kConvDim / 4) return;
  const int c = c4 * 4;
  const int r0 = blockIdx.y * 8;
  const int l0 = r0 & (kL - 1);
  float4 w[4];
  float bias[4];
#pragma unroll
  for (int q = 0; q < 4; q++) {
    w[q] = ((const float4*)conv_w)[c + q];
    bias[q] = conv_b[c + q];
  }
  float v[11][4];
#pragma unroll
  for (int i = 0; i < 11; i++) {
    int l = l0 - 3 + i;
    if (l >= 0) {
      ushort4 t = *(const ushort4*)&zxbcdt[(size_t)(r0 - 3 + i) * kDProj + kDI + c];
      v[i][0] = bu2f(t.x); v[i][1] = bu2f(t.y); v[i][2] = bu2f(t.z); v[i][3] = bu2f(t.w);
    } else {
      v[i][0] = v[i][1] = v[i][2] = v[i][3] = 0.f;
    }
  }
#pragma unroll
  for (int j = 0; j < 8; j++) {
    ushort4 o;
    unsigned short* op = (unsigned short*)&o;
#pragma unroll
    for (int q = 0; q < 4; q++) {
      float a = bias[q] + v[j][q] * w[q].x + v[j + 1][q] * w[q].y +
                v[j + 2][q] * w[q].z + v[j + 3][q] * w[q].w;
      op[q] = f2bu(a / (1.f + expf(-a)));
    }
    *(ushort4*)&xbc_act[(size_t)(r0 + j) * kConvDim + c] = o;
  }
}

// ---- K4: per-(b,chunk,head) end-of-chunk state via MFMA
__global__ __launch_bounds__(256) void chunk_state_kernel(
    const unsigned short* __restrict__ xbc_act,
    const float* __restrict__ dtbuf,
    const float* __restrict__ A_log,
    unsigned short* __restrict__ states,
    float* __restrict__ asum) {
  const int id = blockIdx.x;
  const int h = id & 31;
  const int c = (id >> 5) & (kNC - 1);
  const int b = id >> 11;
  const int tid = threadIdx.x;
  const int wave = tid >> 6, lane = tid & 63;
  __shared__ __align__(16) unsigned short sBT[kDS * kWS];
  __shared__ __align__(16) unsigned short sxd[kCS * kWS];
  __shared__ float s_dt[kCS];
  __shared__ float s_acum[kCS];
  const int l0 = b * kL + c * kCS;
  if (tid < kCS) s_dt[tid] = dtbuf[(size_t)(l0 + tid) * kNH + h];
  __syncthreads();
  if (tid == 0) {
    float A = -expf(A_log[h]);
    float run = 0.f;
    for (int s = 0; s < kCS; s++) { run += A * s_dt[s]; s_acum[s] = run; }
    asum[id] = run;
  }
  __syncthreads();
  const float total = s_acum[kCS - 1];
  for (int e = tid; e < kCS * kDS; e += 256) {
    int s = e >> 7, n = e & 127;
    sBT[n * kWS + s] = xbc_act[(size_t)(l0 + s) * kConvDim + kDI + n];
  }
  for (int e = tid; e < kCS * kHP; e += 256) {
    int s = e >> 6, p = e & 63;
    float xv = bu2f(xbc_act[(size_t)(l0 + s) * kConvDim + h * kHP + p]);
    sxd[p * kWS + s] = f2bu(xv * s_dt[s] * expf(total - s_acum[s]));
  }
  __syncthreads();
  const int arow = wave * 16 + (lane & 15);
  const int fk = (lane >> 4) * 8;
  f32x4 acc[8] = {};
#pragma unroll
  for (int kk = 0; kk < 2; kk++) {
    bf16x8 a = *(const bf16x8*)&sxd[arow * kWS + kk * 32 + fk];
#pragma unroll
    for (int j = 0; j < 8; j++) {
      bf16x8 bb = *(const bf16x8*)&sBT[(j * 16 + (lane & 15)) * kWS + kk * 32 + fk];
      acc[j] = __builtin_amdgcn_mfma_f32_16x16x32_bf16(a, bb, acc[j], 0, 0, 0);
    }
  }
  const int prow = wave * 16 + (lane >> 4) * 4;
  const int ncol = lane & 15;
  size_t base = (size_t)id * (kHP * kDS);
#pragma unroll
  for (int j = 0; j < 8; j++)
#pragma unroll
    for (int r = 0; r < 4; r++)
      states[base + (size_t)(prow + r) * kDS + j * 16 + ncol] = f2bu(acc[j][r]);
}

// ---- K5: sequential inter-chunk scan with software prefetch
__global__ void scan_kernel(unsigned short* __restrict__ states,
                            const float* __restrict__ asum) {
  const int blk = blockIdx.x;
  const int seg = blk & 7;
  const int bh = blk >> 3;
  const int h = bh & 31, b = bh >> 5;
  const int e4 = seg * 256 + threadIdx.x;
  const size_t cstride = (size_t)kNH * 2048;            // ushort4 units per chunk
  ushort4* p = (ushort4*)states + ((size_t)(b * kNC) * kNH + h) * 2048 + e4;
  const float* ap = asum + (b * kNC) * kNH + h;
  float c0 = 0.f, c1 = 0.f, c2 = 0.f, c3 = 0.f;
  ushort4 t = p[0];
  float dec = expf(ap[0]);
  for (int c = 0; c < kNC; c++) {
    ushort4 tn = t;
    float decn = dec;
    if (c + 1 < kNC) {                                  // prefetch next chunk
      tn = p[(size_t)(c + 1) * cstride];
      decn = expf(ap[(c + 1) * kNH]);
    }
    ushort4 o;
    o.x = f2bu(c0); o.y = f2bu(c1); o.z = f2bu(c2); o.w = f2bu(c3);
    p[(size_t)c * cstride] = o;
    c0 = c0 * dec + bu2f(t.x);
    c1 = c1 * dec + bu2f(t.y);
    c2 = c2 * dec + bu2f(t.z);
    c3 = c3 * dec + bu2f(t.w);
    t = tn; dec = decn;
  }
}

// ---- K6: intra-chunk Y, 4 heads/block; Yoff B-frags direct from global
__global__ __launch_bounds__(256) void y_kernel(
    const unsigned short* __restrict__ xbc_act,
    const unsigned short* __restrict__ zxbcdt,
    const unsigned short* __restrict__ states_in,
    const float* __restrict__ dtbuf,
    const float* __restrict__ A_log,
    unsigned short* __restrict__ ybuf,
    float* __restrict__ pS, float* __restrict__ pQ) {
  const int id = blockIdx.x;                 // (b*NC + c)*8 + hg
  const int hg = id & 7;
  const int c = (id >> 3) & (kNC - 1);
  const int b = id >> 9;
  const int tid = threadIdx.x;
  const int wave = tid >> 6, lane = tid & 63;
  __shared__ __align__(16) unsigned short sC[kCS * kTS];
  __shared__ __align__(16) unsigned short sB[kCS * kTS];
  __shared__ __align__(16) unsigned short sxd[kCS * kWS];
  __shared__ __align__(16) unsigned short sW[kCS * kWS];
  __shared__ float s_dt[4][kCS];
  __shared__ float s_acum[4][kCS];
  const int l0 = b * kL + c * kCS;
  {
    int hh = tid >> 6, s = tid & 63;
    s_dt[hh][s] = dtbuf[(size_t)(l0 + s) * kNH + hg * 4 + hh];
  }
  __syncthreads();
  if (tid < 4) {
    float A = -expf(A_log[hg * 4 + tid]);
    float run = 0.f;
    for (int s = 0; s < kCS; s++) { run += A * s_dt[tid][s]; s_acum[tid][s] = run; }
  }
  for (int e = tid; e < kCS * 16; e += 256) {
    int row = e >> 4, c8 = (e & 15) * 8;
    size_t rb = (size_t)(l0 + row) * kConvDim;
    *(ushort8*)&sB[row * kTS + c8] = *(const ushort8*)&xbc_act[rb + kDI + c8];
    *(ushort8*)&sC[row * kTS + c8] = *(const ushort8*)&xbc_act[rb + kDI + kDS + c8];
  }
  __syncthreads();
  const int arow = wave * 16 + (lane & 15);
  const int fk = (lane >> 4) * 8;
  // G[l][s] = C . B^T  (K=128) — head-independent, once per block
  f32x4 accG[4] = {};
#pragma unroll
  for (int kk = 0; kk < 4; kk++) {
    bf16x8 a = *(const bf16x8*)&sC[arow * kTS + kk * 32 + fk];
#pragma unroll
    for (int j = 0; j < 4; j++) {
      bf16x8 bb = *(const bf16x8*)&sB[(j * 16 + (lane & 15)) * kTS + kk * 32 + fk];
      accG[j] = __builtin_amdgcn_mfma_f32_16x16x32_bf16(a, bb, accG[j], 0, 0, 0);
    }
  }
  const int lrow = wave * 16 + (lane >> 4) * 4;
  const size_t sbase = (size_t)((b * kNC + c) * kNH) * (kHP * kDS);
  float rS[4] = {}, rQ[4] = {};
  for (int hh = 0; hh < 4; hh++) {
    const int h = hg * 4 + hh;
    __syncthreads();   // all waves done reading prior head's sxd
    for (int e = tid; e < kCS * kHP; e += 256) {
      int s = e >> 6, p = e & 63;
      float xv = bu2f(xbc_act[(size_t)(l0 + s) * kConvDim + h * kHP + p]);
      sxd[p * kWS + s] = f2bu(xv * s_dt[hh][s]);
    }
#pragma unroll
    for (int j = 0; j < 4; j++) {
      int scol = j * 16 + (lane & 15);
      float as = s_acum[hh][scol];
#pragma unroll
      for (int r = 0; r < 4; r++) {
        int l = lrow + r;
        float w = (scol <= l) ? accG[j][r] * expf(s_acum[hh][l] - as) : 0.f;
        sW[l * kWS + scol] = f2bu(w);
      }
    }
    __syncthreads();
    // Yd = W . xd^T  (K=64)
    f32x4 accY[4] = {};
#pragma unroll
    for (int kk = 0; kk < 2; kk++) {
      bf16x8 a = *(const bf16x8*)&sW[arow * kWS + kk * 32 + fk];
#pragma unroll
      for (int j = 0; j < 4; j++) {
        bf16x8 bb = *(const bf16x8*)&sxd[(j * 16 + (lane & 15)) * kWS + kk * 32 + fk];
        accY[j] = __builtin_amdgcn_mfma_f32_16x16x32_bf16(a, bb, accY[j], 0, 0, 0);
      }
    }
    // Yoff = C . Sin^T  (K=128), Sin B-fragments read directly from global
    const unsigned short* sin_h = states_in + sbase + (size_t)h * (kHP * kDS);
    f32x4 accO[4] = {};
#pragma unroll
    for (int kk = 0; kk < 4; kk++) {
      bf16x8 a = *(const bf16x8*)&sC[arow * kTS + kk * 32 + fk];
#pragma unroll
      for (int j = 0; j < 4; j++) {
        bf16x8 bb = *(const bf16x8*)&sin_h[(size_t)(j * 16 + (lane & 15)) * kDS + kk * 32 + fk];
        accO[j] = __builtin_amdgcn_mfma_f32_16x16x32_bf16(a, bb, accO[j], 0, 0, 0);
      }
    }
#pragma unroll
    for (int r = 0; r < 4; r++) {
      int l = lrow + r;
      float el = expf(s_acum[hh][l]);
      size_t zrow = (size_t)(l0 + l) * kDProj + h * kHP;
      size_t yrow = (size_t)(l0 + l) * kDI + h * kHP;
#pragma unroll
      for (int j = 0; j < 4; j++) {
        int p = j * 16 + (lane & 15);
        float yv = accY[j][r] + el * accO[j][r];
        float z = bu2f(zxbcdt[zrow + p]);
        yv *= z / (1.f + expf(-z));
        rS[r] += yv;
        rQ[r] += yv * yv;
        ybuf[yrow + p] = f2bu(yv);
      }
    }
  }
#pragma unroll
  for (int m = 1; m < 16; m <<= 1) {
#pragma unroll
    for (int r = 0; r < 4; r++) {
      rS[r] += __shfl_xor(rS[r], m);
      rQ[r] += __shfl_xor(rQ[r], m);
    }
  }
  if ((lane & 15) == 0) {
#pragma unroll
    for (int r = 0; r < 4; r++) {
      int row = l0 + lrow + r;
      pS[(size_t)row * 8 + hg] = rS[r];
      pQ[(size_t)row * 8 + hg] = rQ[r];
    }
  }
}

}  // namespace

extern "C" void kernel_launch(void* const* d_in, const int* in_sizes, int n_in,
                              void* d_out, int out_size, void* d_ws, size_t ws_size,
                              hipStream_t stream) {
  const float* u       = (const float*)d_in[0];
  const float* W_in    = (const float*)d_in[1];
  const float* conv_w  = (const float*)d_in[2];
  const float* conv_b  = (const float*)d_in[3];
  const float* dt_bias = (const float*)d_in[4];
  const float* A_log   = (const float*)d_in[5];
  const float* norm_w  = (const float*)d_in[6];
  const float* norm_b  = (const float*)d_in[7];
  const float* W_out   = (const float*)d_in[8];
  float* out = (float*)d_out;

  char* ws = (char*)d_ws;
  size_t off = 0;
  auto alloc = [&](size_t bytes) {
    void* p = ws + off;
    off += (bytes + 255) & ~(size_t)255;
    return p;
  };
  unsigned short* zxbcdt = (unsigned short*)alloc((size_t)kRows * kDProj * 2);        // 71.8 MB
  unsigned short* xbc    = (unsigned short*)alloc((size_t)kRows * kConvDim * 2);      // 37.7 MB
  float* dtb             = (float*)alloc((size_t)kRows * kNH * 4);                    //  1.0 MB
  float* asum            = (float*)alloc((size_t)kB * kNC * kNH * 4);                 // 16 KB
  unsigned short* A1     = (unsigned short*)alloc((size_t)kRows * 1024 * 2);          // 16.8 MB
  unsigned short* Bt1    = (unsigned short*)alloc((size_t)kDProjP * 1024 * 2);        //  9.2 MB
  unsigned short* states = (unsigned short*)alloc((size_t)kB * kNC * kNH * kHP * kDS * 2); // 67.1 MB
  unsigned short* Bt2    = (unsigned short*)alloc((size_t)1024 * kDI * 2);            //  4.2 MB
  unsigned short* ybuf   = (unsigned short*)alloc((size_t)kRows * kDI * 2);           // 33.6 MB
  float* t1              = (float*)alloc(1024 * 4);
  float* t2              = (float*)alloc(1024 * 4);
  float* pS              = (float*)alloc((size_t)kRows * 8 * 4);                      // 256 KB
  float* pQ              = (float*)alloc((size_t)kRows * 8 * 4);                      // 256 KB
  (void)ws_size; (void)in_sizes; (void)n_in; (void)out_size;

  // P: cast + transposes + colsum in one dispatch
  prep_kernel<<<8192 + 140 * 32 + 32 * 64 + 16, 256, 0, stream>>>(
      u, A1, W_in, Bt1, W_out, Bt2, norm_w, norm_b, t1, t2);
  // K1: zxbcdt = u @ W_in, dt folded into epilogue
  gemm_bt<unsigned short, false, true><<<dim3(kDProjP / 128, kRows / 128), 256, 0, stream>>>(
      A1, Bt1, zxbcdt, kRows, kDProj, 1024, nullptr, nullptr, nullptr, nullptr, dt_bias, dtb);
  // K3: conv + silu
  conv_silu_kernel<<<dim3(3, kRows / 8), 256, 0, stream>>>(zxbcdt, conv_w, conv_b, xbc);
  // K4: per-chunk states
  chunk_state_kernel<<<kB * kNC * kNH, 256, 0, stream>>>(xbc, dtb, A_log, states, asum);
  // K5: inter-chunk scan
  scan_kernel<<<kB * kNH * 8, 256, 0, stream>>>(states, asum);
  // K6: Y + gate + LN partials
  y_kernel<<<kB * kNC * 8, 256, 0, stream>>>(xbc, zxbcdt, states, dtb, A_log, ybuf, pS, pQ);
  // K8: out = LN(y) @ W_out (stats derived in prologue, LN folded in epilogue)
  gemm_bt<float, true, false><<<dim3(1024 / 128, kRows / 128), 256, 0, stream>>>(
      ybuf, Bt2, out, kRows, 1024, 2048, pS, pQ, t1, t2, nullptr, nullptr);
}

// Round 8
// 481.616 us; speedup vs baseline: 1.1938x; 1.1938x over previous
//
#include <hip/hip_runtime.h>
#include <hip/hip_bf16.h>
#include <math.h>

// ---------------------------------------------------------------------------
// Mamba2 forward, MI355X. Round 8: revert the round-7 kernel merge (one
// register budget + straggler-section tail made prep 4x slower); keep the
// round-7 folds:
//   C0 cast, C1/C2 transpose, C3 colsum (separate small dispatches)
//   K1 gemm_bt<DT>   : zxbcdt = u @ W_in, dt=softplus folded into epilogue
//   K3 conv_silu     : ushort4-vectorized, 8 rows x 4 cols per thread
//   K4 chunk_state   : MFMA per (b,chunk,head)
//   K5 scan          : inter-chunk scan with software prefetch
//   K6 y_kernel      : 4 heads/block; G once; Sin B-frags direct from global;
//                      emits LN partial sums
//   K8 gemm_bt<FOLD> : out = LN(y) @ W_out; mu/rstd derived in prologue
// ---------------------------------------------------------------------------

namespace {

constexpr int kB   = 2;
constexpr int kL   = 4096;
constexpr int kDI  = 2048;
constexpr int kDS  = 128;
constexpr int kNH  = 32;
constexpr int kHP  = 64;
constexpr int kDC  = 4;
constexpr int kCS  = 64;
constexpr int kNC  = kL / kCS;
constexpr int kDProj   = 2 * kDI + 2 * kDS + kNH;  // 4384
constexpr int kDProjP  = 4480;                     // 35*128
constexpr int kConvDim = kDI + 2 * kDS;            // 2304
constexpr int kRows = kB * kL;                     // 8192
constexpr float kEps = 1e-5f;
constexpr int kTS = 136;   // LDS stride for [64][128] tiles
constexpr int kWS = 72;    // LDS stride for [64][64] tiles

typedef __bf16 bf16x8 __attribute__((ext_vector_type(8)));
typedef float f32x4 __attribute__((ext_vector_type(4)));
typedef unsigned short ushort8 __attribute__((ext_vector_type(8)));

__device__ inline float bu2f(unsigned short u) {
  union { unsigned int i; float f; } x; x.i = ((unsigned int)u) << 16; return x.f;
}
__device__ inline unsigned short f2bu(float f) {
  __hip_bfloat16 h = __float2bfloat16(f);
  return *reinterpret_cast<unsigned short*>(&h);
}

__device__ inline void store_out(float* C, size_t i, float v) { C[i] = v; }
__device__ inline void store_out(unsigned short* C, size_t i, float v) { C[i] = f2bu(v); }

__device__ inline void gld_lds16(const unsigned short* g, unsigned short* l) {
  __builtin_amdgcn_global_load_lds(
      (const __attribute__((address_space(1))) unsigned int*)g,
      (__attribute__((address_space(3))) unsigned int*)l, 16, 0, 0);
}

// ---- C0: cast fp32 -> bf16
__global__ void cast_kernel(const float4* __restrict__ in, ushort4* __restrict__ out, int n4) {
  int i = blockIdx.x * 256 + threadIdx.x;
  if (i >= n4) return;
  float4 v = in[i];
  ushort4 o;
  o.x = f2bu(v.x); o.y = f2bu(v.y); o.z = f2bu(v.z); o.w = f2bu(v.w);
  out[i] = o;
}

// ---- C1/C2: transpose + cast (+optional per-row scale)
__global__ void transpose_cast(const float* __restrict__ in, unsigned short* __restrict__ out,
                               int R, int C, const float* __restrict__ scale) {
  __shared__ float t[32][33];
  const int c0 = blockIdx.x * 32;
  const int r0 = blockIdx.y * 32;
  const int tx = threadIdx.x & 31, ty = threadIdx.x >> 5;
  for (int rr = ty; rr < 32; rr += 8) {
    int c = c0 + tx;
    float v = (c < C) ? in[(size_t)(r0 + rr) * C + c] : 0.f;
    if (scale) v *= scale[r0 + rr];
    t[rr][tx] = v;
  }
  __syncthreads();
  for (int cc = ty; cc < 32; cc += 8) {
    int orow = c0 + cc;
    out[(size_t)orow * R + r0 + tx] = f2bu(t[tx][cc]);
  }
}

// ---- C3: t1[n] = sum_k w[k]*W2[k][n], t2[n] = sum_k b[k]*W2[k][n]
__global__ void colsum_kernel(const float* __restrict__ W2, const float* __restrict__ wv,
                              const float* __restrict__ bv,
                              float* __restrict__ t1, float* __restrict__ t2) {
  __shared__ float p1[4][64], p2[4][64];
  const int nl = threadIdx.x & 63;
  const int ks = threadIdx.x >> 6;
  const int n = blockIdx.x * 64 + nl;
  float s1 = 0.f, s2 = 0.f;
  for (int k = ks * 512; k < ks * 512 + 512; k++) {
    float v = W2[(size_t)k * 1024 + n];
    s1 += wv[k] * v;
    s2 += bv[k] * v;
  }
  p1[ks][nl] = s1; p2[ks][nl] = s2;
  __syncthreads();
  if (threadIdx.x < 64) {
    t1[blockIdx.x * 64 + threadIdx.x] =
        p1[0][threadIdx.x] + p1[1][threadIdx.x] + p1[2][threadIdx.x] + p1[3][threadIdx.x];
    t2[blockIdx.x * 64 + threadIdx.x] =
        p2[0][threadIdx.x] + p2[1][threadIdx.x] + p2[2][threadIdx.x] + p2[3][threadIdx.x];
  }
}

// ---- MFMA GEMM, XOR-swizzled LDS. DT: fold softplus-dt; FOLD: fold LayerNorm.
template <typename OutT, bool FOLD, bool DT>
__global__ __launch_bounds__(256) void gemm_bt(const unsigned short* __restrict__ A,
                                               const unsigned short* __restrict__ Bt,
                                               OutT* __restrict__ C, int M, int N, int K,
                                               const float* __restrict__ pS,
                                               const float* __restrict__ pQ,
                                               const float* __restrict__ t1,
                                               const float* __restrict__ t2,
                                               const float* __restrict__ dt_bias,
                                               float* __restrict__ dtbuf) {
  __shared__ __align__(16) unsigned short As[128 * 32];
  __shared__ __align__(16) unsigned short Bs[128 * 32];
  __shared__ float smu[128], srstd[128];
  const int tid = threadIdx.x;
  const int wave = tid >> 6, lane = tid & 63;
  const int m0 = blockIdx.y * 128, n0 = blockIdx.x * 128;
  if (FOLD && tid < 128) {                // LN stats for this block's 128 rows
    int row = m0 + tid;
    float s = 0.f, q = 0.f;
#pragma unroll
    for (int i = 0; i < 8; i++) { s += pS[(size_t)row * 8 + i]; q += pQ[(size_t)row * 8 + i]; }
    float m = s / kDI;
    smu[tid] = m;
    srstd[tid] = rsqrtf(q / kDI - m * m + kEps);
  }
  const int wr = (wave >> 1) * 64, wc = (wave & 1) * 64;
  const int st_row = lane >> 2;
  const int st_col = (((lane & 3) ^ ((st_row >> 1) & 3))) * 8;  // XOR swizzle
  const unsigned short* pA[2];
  const unsigned short* pB[2];
  unsigned short* lA[2];
  unsigned short* lB[2];
#pragma unroll
  for (int r = 0; r < 2; r++) {
    int q = wave * 2 + r;
    pA[r] = A + (size_t)(m0 + q * 16 + st_row) * K + st_col;
    pB[r] = Bt + (size_t)(n0 + q * 16 + st_row) * K + st_col;
    lA[r] = &As[q * 512];
    lB[r] = &Bs[q * 512];
  }
  const int frag_row = lane & 15;
  const int rk = (((lane >> 4) ^ ((frag_row >> 1) & 3))) * 8;
  f32x4 acc[4][4] = {};
  for (int k0 = 0; k0 < K; k0 += 32) {
#pragma unroll
    for (int r = 0; r < 2; r++) {
      gld_lds16(pA[r] + k0, lA[r]);
      gld_lds16(pB[r] + k0, lB[r]);
    }
    asm volatile("s_waitcnt vmcnt(0)" ::: "memory");
    __syncthreads();
    bf16x8 af[4], bfr[4];
#pragma unroll
    for (int i = 0; i < 4; i++)
      af[i] = *(const bf16x8*)&As[(wr + i * 16 + frag_row) * 32 + rk];
#pragma unroll
    for (int j = 0; j < 4; j++)
      bfr[j] = *(const bf16x8*)&Bs[(wc + j * 16 + frag_row) * 32 + rk];
#pragma unroll
    for (int i = 0; i < 4; i++)
#pragma unroll
      for (int j = 0; j < 4; j++)
        acc[i][j] = __builtin_amdgcn_mfma_f32_16x16x32_bf16(af[i], bfr[j], acc[i][j], 0, 0, 0);
    __syncthreads();
  }
  const int crow = (lane >> 4) * 4;
  const int ccol = lane & 15;
#pragma unroll
  for (int i = 0; i < 4; i++) {
#pragma unroll
    for (int j = 0; j < 4; j++) {
      int n = n0 + wc + j * 16 + ccol;
      if (n < N) {
        float c1 = FOLD ? t1[n] : 0.f;
        float c2 = FOLD ? t2[n] : 0.f;
        bool isdt = DT && (n >= N - kNH);
        float db = isdt ? dt_bias[n - (N - kNH)] : 0.f;
#pragma unroll
        for (int r = 0; r < 4; r++) {
          int m = m0 + wr + i * 16 + crow + r;
          float v = acc[i][j][r];
          if (FOLD) v = srstd[m - m0] * (v - smu[m - m0] * c1) + c2;
          store_out(C, (size_t)m * N + n, v);
          if (isdt) {
            float x = acc[i][j][r] + db;
            dtbuf[(size_t)m * kNH + (n - (N - kNH))] = (x > 15.f) ? x : log1pf(expf(x));
          }
        }
      }
    }
  }
}

// ---- K3: causal depthwise conv (k=4) + SiLU, 8 rows x 4 cols per thread
__global__ void conv_silu_kernel(const unsigned short* __restrict__ zxbcdt,
                                 const float* __restrict__ conv_w,
                                 const float* __restrict__ conv_b,
                                 unsigned short* __restrict__ xbc_act) {
  int c4 = blockIdx.x * 256 + threadIdx.x;
  if (c4 >= kConvDim / 4) return;
  const int c = c4 * 4;
  const int r0 = blockIdx.y * 8;
  const int l0 = r0 & (kL - 1);
  float4 w[4];
  float bias[4];
#pragma unroll
  for (int q = 0; q < 4; q++) {
    w[q] = ((const float4*)conv_w)[c + q];
    bias[q] = conv_b[c + q];
  }
  float v[11][4];
#pragma unroll
  for (int i = 0; i < 11; i++) {
    int l = l0 - 3 + i;
    if (l >= 0) {
      ushort4 t = *(const ushort4*)&zxbcdt[(size_t)(r0 - 3 + i) * kDProj + kDI + c];
      v[i][0] = bu2f(t.x); v[i][1] = bu2f(t.y); v[i][2] = bu2f(t.z); v[i][3] = bu2f(t.w);
    } else {
      v[i][0] = v[i][1] = v[i][2] = v[i][3] = 0.f;
    }
  }
#pragma unroll
  for (int j = 0; j < 8; j++) {
    ushort4 o;
    unsigned short* op = (unsigned short*)&o;
#pragma unroll
    for (int q = 0; q < 4; q++) {
      float a = bias[q] + v[j][q] * w[q].x + v[j + 1][q] * w[q].y +
                v[j + 2][q] * w[q].z + v[j + 3][q] * w[q].w;
      op[q] = f2bu(a / (1.f + expf(-a)));
    }
    *(ushort4*)&xbc_act[(size_t)(r0 + j) * kConvDim + c] = o;
  }
}

// ---- K4: per-(b,chunk,head) end-of-chunk state via MFMA
__global__ __launch_bounds__(256) void chunk_state_kernel(
    const unsigned short* __restrict__ xbc_act,
    const float* __restrict__ dtbuf,
    const float* __restrict__ A_log,
    unsigned short* __restrict__ states,
    float* __restrict__ asum) {
  const int id = blockIdx.x;
  const int h = id & 31;
  const int c = (id >> 5) & (kNC - 1);
  const int b = id >> 11;
  const int tid = threadIdx.x;
  const int wave = tid >> 6, lane = tid & 63;
  __shared__ __align__(16) unsigned short sBT[kDS * kWS];
  __shared__ __align__(16) unsigned short sxd[kCS * kWS];
  __shared__ float s_dt[kCS];
  __shared__ float s_acum[kCS];
  const int l0 = b * kL + c * kCS;
  if (tid < kCS) s_dt[tid] = dtbuf[(size_t)(l0 + tid) * kNH + h];
  __syncthreads();
  if (tid == 0) {
    float A = -expf(A_log[h]);
    float run = 0.f;
    for (int s = 0; s < kCS; s++) { run += A * s_dt[s]; s_acum[s] = run; }
    asum[id] = run;
  }
  __syncthreads();
  const float total = s_acum[kCS - 1];
  for (int e = tid; e < kCS * kDS; e += 256) {
    int s = e >> 7, n = e & 127;
    sBT[n * kWS + s] = xbc_act[(size_t)(l0 + s) * kConvDim + kDI + n];
  }
  for (int e = tid; e < kCS * kHP; e += 256) {
    int s = e >> 6, p = e & 63;
    float xv = bu2f(xbc_act[(size_t)(l0 + s) * kConvDim + h * kHP + p]);
    sxd[p * kWS + s] = f2bu(xv * s_dt[s] * expf(total - s_acum[s]));
  }
  __syncthreads();
  const int arow = wave * 16 + (lane & 15);
  const int fk = (lane >> 4) * 8;
  f32x4 acc[8] = {};
#pragma unroll
  for (int kk = 0; kk < 2; kk++) {
    bf16x8 a = *(const bf16x8*)&sxd[arow * kWS + kk * 32 + fk];
#pragma unroll
    for (int j = 0; j < 8; j++) {
      bf16x8 bb = *(const bf16x8*)&sBT[(j * 16 + (lane & 15)) * kWS + kk * 32 + fk];
      acc[j] = __builtin_amdgcn_mfma_f32_16x16x32_bf16(a, bb, acc[j], 0, 0, 0);
    }
  }
  const int prow = wave * 16 + (lane >> 4) * 4;
  const int ncol = lane & 15;
  size_t base = (size_t)id * (kHP * kDS);
#pragma unroll
  for (int j = 0; j < 8; j++)
#pragma unroll
    for (int r = 0; r < 4; r++)
      states[base + (size_t)(prow + r) * kDS + j * 16 + ncol] = f2bu(acc[j][r]);
}

// ---- K5: sequential inter-chunk scan with software prefetch
__global__ void scan_kernel(unsigned short* __restrict__ states,
                            const float* __restrict__ asum) {
  const int blk = blockIdx.x;
  const int seg = blk & 7;
  const int bh = blk >> 3;
  const int h = bh & 31, b = bh >> 5;
  const int e4 = seg * 256 + threadIdx.x;
  const size_t cstride = (size_t)kNH * 2048;            // ushort4 units per chunk
  ushort4* p = (ushort4*)states + ((size_t)(b * kNC) * kNH + h) * 2048 + e4;
  const float* ap = asum + (b * kNC) * kNH + h;
  float c0 = 0.f, c1 = 0.f, c2 = 0.f, c3 = 0.f;
  ushort4 t = p[0];
  float dec = expf(ap[0]);
  for (int c = 0; c < kNC; c++) {
    ushort4 tn = t;
    float decn = dec;
    if (c + 1 < kNC) {                                  // prefetch next chunk
      tn = p[(size_t)(c + 1) * cstride];
      decn = expf(ap[(c + 1) * kNH]);
    }
    ushort4 o;
    o.x = f2bu(c0); o.y = f2bu(c1); o.z = f2bu(c2); o.w = f2bu(c3);
    p[(size_t)c * cstride] = o;
    c0 = c0 * dec + bu2f(t.x);
    c1 = c1 * dec + bu2f(t.y);
    c2 = c2 * dec + bu2f(t.z);
    c3 = c3 * dec + bu2f(t.w);
    t = tn; dec = decn;
  }
}

// ---- K6: intra-chunk Y, 4 heads/block; Sin B-frags direct from global
__global__ __launch_bounds__(256) void y_kernel(
    const unsigned short* __restrict__ xbc_act,
    const unsigned short* __restrict__ zxbcdt,
    const unsigned short* __restrict__ states_in,
    const float* __restrict__ dtbuf,
    const float* __restrict__ A_log,
    unsigned short* __restrict__ ybuf,
    float* __restrict__ pS, float* __restrict__ pQ) {
  const int id = blockIdx.x;                 // (b*NC + c)*8 + hg
  const int hg = id & 7;
  const int c = (id >> 3) & (kNC - 1);
  const int b = id >> 9;
  const int tid = threadIdx.x;
  const int wave = tid >> 6, lane = tid & 63;
  __shared__ __align__(16) unsigned short sC[kCS * kTS];
  __shared__ __align__(16) unsigned short sB[kCS * kTS];
  __shared__ __align__(16) unsigned short sxd[kCS * kWS];
  __shared__ __align__(16) unsigned short sW[kCS * kWS];
  __shared__ float s_dt[4][kCS];
  __shared__ float s_acum[4][kCS];
  const int l0 = b * kL + c * kCS;
  {
    int hh = tid >> 6, s = tid & 63;
    s_dt[hh][s] = dtbuf[(size_t)(l0 + s) * kNH + hg * 4 + hh];
  }
  __syncthreads();
  if (tid < 4) {
    float A = -expf(A_log[hg * 4 + tid]);
    float run = 0.f;
    for (int s = 0; s < kCS; s++) { run += A * s_dt[tid][s]; s_acum[tid][s] = run; }
  }
  for (int e = tid; e < kCS * 16; e += 256) {
    int row = e >> 4, c8 = (e & 15) * 8;
    size_t rb = (size_t)(l0 + row) * kConvDim;
    *(ushort8*)&sB[row * kTS + c8] = *(const ushort8*)&xbc_act[rb + kDI + c8];
    *(ushort8*)&sC[row * kTS + c8] = *(const ushort8*)&xbc_act[rb + kDI + kDS + c8];
  }
  __syncthreads();
  const int arow = wave * 16 + (lane & 15);
  const int fk = (lane >> 4) * 8;
  // G[l][s] = C . B^T  (K=128) — head-independent, once per block
  f32x4 accG[4] = {};
#pragma unroll
  for (int kk = 0; kk < 4; kk++) {
    bf16x8 a = *(const bf16x8*)&sC[arow * kTS + kk * 32 + fk];
#pragma unroll
    for (int j = 0; j < 4; j++) {
      bf16x8 bb = *(const bf16x8*)&sB[(j * 16 + (lane & 15)) * kTS + kk * 32 + fk];
      accG[j] = __builtin_amdgcn_mfma_f32_16x16x32_bf16(a, bb, accG[j], 0, 0, 0);
    }
  }
  const int lrow = wave * 16 + (lane >> 4) * 4;
  const size_t sbase = (size_t)((b * kNC + c) * kNH) * (kHP * kDS);
  float rS[4] = {}, rQ[4] = {};
  for (int hh = 0; hh < 4; hh++) {
    const int h = hg * 4 + hh;
    __syncthreads();   // all waves done reading prior head's sxd
    for (int e = tid; e < kCS * kHP; e += 256) {
      int s = e >> 6, p = e & 63;
      float xv = bu2f(xbc_act[(size_t)(l0 + s) * kConvDim + h * kHP + p]);
      sxd[p * kWS + s] = f2bu(xv * s_dt[hh][s]);
    }
#pragma unroll
    for (int j = 0; j < 4; j++) {
      int scol = j * 16 + (lane & 15);
      float as = s_acum[hh][scol];
#pragma unroll
      for (int r = 0; r < 4; r++) {
        int l = lrow + r;
        float w = (scol <= l) ? accG[j][r] * expf(s_acum[hh][l] - as) : 0.f;
        sW[l * kWS + scol] = f2bu(w);
      }
    }
    __syncthreads();
    // Yd = W . xd^T  (K=64)
    f32x4 accY[4] = {};
#pragma unroll
    for (int kk = 0; kk < 2; kk++) {
      bf16x8 a = *(const bf16x8*)&sW[arow * kWS + kk * 32 + fk];
#pragma unroll
      for (int j = 0; j < 4; j++) {
        bf16x8 bb = *(const bf16x8*)&sxd[(j * 16 + (lane & 15)) * kWS + kk * 32 + fk];
        accY[j] = __builtin_amdgcn_mfma_f32_16x16x32_bf16(a, bb, accY[j], 0, 0, 0);
      }
    }
    // Yoff = C . Sin^T  (K=128), Sin B-fragments read directly from global
    const unsigned short* sin_h = states_in + sbase + (size_t)h * (kHP * kDS);
    f32x4 accO[4] = {};
#pragma unroll
    for (int kk = 0; kk < 4; kk++) {
      bf16x8 a = *(const bf16x8*)&sC[arow * kTS + kk * 32 + fk];
#pragma unroll
      for (int j = 0; j < 4; j++) {
        bf16x8 bb = *(const bf16x8*)&sin_h[(size_t)(j * 16 + (lane & 15)) * kDS + kk * 32 + fk];
        accO[j] = __builtin_amdgcn_mfma_f32_16x16x32_bf16(a, bb, accO[j], 0, 0, 0);
      }
    }
#pragma unroll
    for (int r = 0; r < 4; r++) {
      int l = lrow + r;
      float el = expf(s_acum[hh][l]);
      size_t zrow = (size_t)(l0 + l) * kDProj + h * kHP;
      size_t yrow = (size_t)(l0 + l) * kDI + h * kHP;
#pragma unroll
      for (int j = 0; j < 4; j++) {
        int p = j * 16 + (lane & 15);
        float yv = accY[j][r] + el * accO[j][r];
        float z = bu2f(zxbcdt[zrow + p]);
        yv *= z / (1.f + expf(-z));
        rS[r] += yv;
        rQ[r] += yv * yv;
        ybuf[yrow + p] = f2bu(yv);
      }
    }
  }
#pragma unroll
  for (int m = 1; m < 16; m <<= 1) {
#pragma unroll
    for (int r = 0; r < 4; r++) {
      rS[r] += __shfl_xor(rS[r], m);
      rQ[r] += __shfl_xor(rQ[r], m);
    }
  }
  if ((lane & 15) == 0) {
#pragma unroll
    for (int r = 0; r < 4; r++) {
      int row = l0 + lrow + r;
      pS[(size_t)row * 8 + hg] = rS[r];
      pQ[(size_t)row * 8 + hg] = rQ[r];
    }
  }
}

}  // namespace

extern "C" void kernel_launch(void* const* d_in, const int* in_sizes, int n_in,
                              void* d_out, int out_size, void* d_ws, size_t ws_size,
                              hipStream_t stream) {
  const float* u       = (const float*)d_in[0];
  const float* W_in    = (const float*)d_in[1];
  const float* conv_w  = (const float*)d_in[2];
  const float* conv_b  = (const float*)d_in[3];
  const float* dt_bias = (const float*)d_in[4];
  const float* A_log   = (const float*)d_in[5];
  const float* norm_w  = (const float*)d_in[6];
  const float* norm_b  = (const float*)d_in[7];
  const float* W_out   = (const float*)d_in[8];
  float* out = (float*)d_out;

  char* ws = (char*)d_ws;
  size_t off = 0;
  auto alloc = [&](size_t bytes) {
    void* p = ws + off;
    off += (bytes + 255) & ~(size_t)255;
    return p;
  };
  unsigned short* zxbcdt = (unsigned short*)alloc((size_t)kRows * kDProj * 2);        // 71.8 MB
  unsigned short* xbc    = (unsigned short*)alloc((size_t)kRows * kConvDim * 2);      // 37.7 MB
  float* dtb             = (float*)alloc((size_t)kRows * kNH * 4);                    //  1.0 MB
  float* asum            = (float*)alloc((size_t)kB * kNC * kNH * 4);                 // 16 KB
  unsigned short* A1     = (unsigned short*)alloc((size_t)kRows * 1024 * 2);          // 16.8 MB
  unsigned short* Bt1    = (unsigned short*)alloc((size_t)kDProjP * 1024 * 2);        //  9.2 MB
  unsigned short* states = (unsigned short*)alloc((size_t)kB * kNC * kNH * kHP * kDS * 2); // 67.1 MB
  unsigned short* Bt2    = (unsigned short*)alloc((size_t)1024 * kDI * 2);            //  4.2 MB
  unsigned short* ybuf   = (unsigned short*)alloc((size_t)kRows * kDI * 2);           // 33.6 MB
  float* t1              = (float*)alloc(1024 * 4);
  float* t2              = (float*)alloc(1024 * 4);
  float* pS              = (float*)alloc((size_t)kRows * 8 * 4);                      // 256 KB
  float* pQ              = (float*)alloc((size_t)kRows * 8 * 4);                      // 256 KB
  (void)ws_size; (void)in_sizes; (void)n_in; (void)out_size;

  // C0..C3: prep as separate small dispatches (round-6 structure)
  cast_kernel<<<(kRows * 1024 / 4 + 255) / 256, 256, 0, stream>>>(
      (const float4*)u, (ushort4*)A1, kRows * 1024 / 4);
  transpose_cast<<<dim3(kDProjP / 32, 1024 / 32), 256, 0, stream>>>(
      W_in, Bt1, 1024, kDProj, nullptr);
  transpose_cast<<<dim3(1024 / 32, 2048 / 32), 256, 0, stream>>>(
      W_out, Bt2, 2048, 1024, norm_w);
  colsum_kernel<<<16, 256, 0, stream>>>(W_out, norm_w, norm_b, t1, t2);
  // K1: zxbcdt = u @ W_in, dt folded into epilogue
  gemm_bt<unsigned short, false, true><<<dim3(kDProjP / 128, kRows / 128), 256, 0, stream>>>(
      A1, Bt1, zxbcdt, kRows, kDProj, 1024, nullptr, nullptr, nullptr, nullptr, dt_bias, dtb);
  // K3: conv + silu
  conv_silu_kernel<<<dim3(3, kRows / 8), 256, 0, stream>>>(zxbcdt, conv_w, conv_b, xbc);
  // K4: per-chunk states
  chunk_state_kernel<<<kB * kNC * kNH, 256, 0, stream>>>(xbc, dtb, A_log, states, asum);
  // K5: inter-chunk scan
  scan_kernel<<<kB * kNH * 8, 256, 0, stream>>>(states, asum);
  // K6: Y + gate + LN partials
  y_kernel<<<kB * kNC * 8, 256, 0, stream>>>(xbc, zxbcdt, states, dtb, A_log, ybuf, pS, pQ);
  // K8: out = LN(y) @ W_out (stats in prologue, LN folded in epilogue)
  gemm_bt<float, true, false><<<dim3(1024 / 128, kRows / 128), 256, 0, stream>>>(
      ybuf, Bt2, out, kRows, 1024, 2048, pS, pQ, t1, t2, nullptr, nullptr);
}

// Round 9
// 454.919 us; speedup vs baseline: 1.2639x; 1.0587x over previous
//
#include <hip/hip_runtime.h>
#include <hip/hip_bf16.h>
#include <math.h>

// ---------------------------------------------------------------------------
// Mamba2 forward, MI355X. Round 9: round-6 structure (best measured: 457.7us)
// + only two isolated, register-budget-neutral upgrades:
//   - conv_silu: ushort4-vectorized (8 rows x 4 cols per thread)
//   - scan: software prefetch of next chunk
// Everything else byte-identical to round 6:
//   C0 cast, C1/C2 transpose, C3 colsum, K1 gemm_bt (VGPR 72, XOR swizzle),
//   K2 dt, K4 chunk_state, K5 scan, K6 y (4 heads/blk, LN partials),
//   K7 ln_reduce, K8 gemm_bt FOLD.
// ---------------------------------------------------------------------------

namespace {

constexpr int kB   = 2;
constexpr int kL   = 4096;
constexpr int kDI  = 2048;
constexpr int kDS  = 128;
constexpr int kNH  = 32;
constexpr int kHP  = 64;
constexpr int kDC  = 4;
constexpr int kCS  = 64;
constexpr int kNC  = kL / kCS;
constexpr int kDProj   = 2 * kDI + 2 * kDS + kNH;  // 4384
constexpr int kDProjP  = 4480;                     // 35*128
constexpr int kConvDim = kDI + 2 * kDS;            // 2304
constexpr int kRows = kB * kL;                     // 8192
constexpr float kEps = 1e-5f;
constexpr int kTS = 136;   // LDS stride for [64][128] tiles
constexpr int kWS = 72;    // LDS stride for [64][64] tiles

typedef __bf16 bf16x8 __attribute__((ext_vector_type(8)));
typedef float f32x4 __attribute__((ext_vector_type(4)));
typedef unsigned short ushort8 __attribute__((ext_vector_type(8)));

__device__ inline float bu2f(unsigned short u) {
  union { unsigned int i; float f; } x; x.i = ((unsigned int)u) << 16; return x.f;
}
__device__ inline unsigned short f2bu(float f) {
  __hip_bfloat16 h = __float2bfloat16(f);
  return *reinterpret_cast<unsigned short*>(&h);
}

__device__ inline void store_out(float* C, size_t i, float v) { C[i] = v; }
__device__ inline void store_out(unsigned short* C, size_t i, float v) { C[i] = f2bu(v); }

__device__ inline void gld_lds16(const unsigned short* g, unsigned short* l) {
  __builtin_amdgcn_global_load_lds(
      (const __attribute__((address_space(1))) unsigned int*)g,
      (__attribute__((address_space(3))) unsigned int*)l, 16, 0, 0);
}

// ---- C0: cast fp32 -> bf16
__global__ void cast_kernel(const float4* __restrict__ in, ushort4* __restrict__ out, int n4) {
  int i = blockIdx.x * 256 + threadIdx.x;
  if (i >= n4) return;
  float4 v = in[i];
  ushort4 o;
  o.x = f2bu(v.x); o.y = f2bu(v.y); o.z = f2bu(v.z); o.w = f2bu(v.w);
  out[i] = o;
}

// ---- C1/C2: transpose + cast (+optional per-row scale)
__global__ void transpose_cast(const float* __restrict__ in, unsigned short* __restrict__ out,
                               int R, int C, const float* __restrict__ scale) {
  __shared__ float t[32][33];
  const int c0 = blockIdx.x * 32;
  const int r0 = blockIdx.y * 32;
  const int tx = threadIdx.x & 31, ty = threadIdx.x >> 5;
  for (int rr = ty; rr < 32; rr += 8) {
    int c = c0 + tx;
    float v = (c < C) ? in[(size_t)(r0 + rr) * C + c] : 0.f;
    if (scale) v *= scale[r0 + rr];
    t[rr][tx] = v;
  }
  __syncthreads();
  for (int cc = ty; cc < 32; cc += 8) {
    int orow = c0 + cc;
    out[(size_t)orow * R + r0 + tx] = f2bu(t[tx][cc]);
  }
}

// ---- C3: t1[n] = sum_k w[k]*W2[k][n], t2[n] = sum_k b[k]*W2[k][n]
__global__ void colsum_kernel(const float* __restrict__ W2, const float* __restrict__ wv,
                              const float* __restrict__ bv,
                              float* __restrict__ t1, float* __restrict__ t2) {
  __shared__ float p1[4][64], p2[4][64];
  const int nl = threadIdx.x & 63;
  const int ks = threadIdx.x >> 6;
  const int n = blockIdx.x * 64 + nl;
  float s1 = 0.f, s2 = 0.f;
  for (int k = ks * 512; k < ks * 512 + 512; k++) {
    float v = W2[(size_t)k * 1024 + n];
    s1 += wv[k] * v;
    s2 += bv[k] * v;
  }
  p1[ks][nl] = s1; p2[ks][nl] = s2;
  __syncthreads();
  if (threadIdx.x < 64) {
    t1[blockIdx.x * 64 + threadIdx.x] =
        p1[0][threadIdx.x] + p1[1][threadIdx.x] + p1[2][threadIdx.x] + p1[3][threadIdx.x];
    t2[blockIdx.x * 64 + threadIdx.x] =
        p2[0][threadIdx.x] + p2[1][threadIdx.x] + p2[2][threadIdx.x] + p2[3][threadIdx.x];
  }
}

// ---- MFMA GEMM with XOR-swizzled LDS. FOLD applies LayerNorm in epilogue.
template <typename OutT, bool FOLD>
__global__ __launch_bounds__(256) void gemm_bt(const unsigned short* __restrict__ A,
                                               const unsigned short* __restrict__ Bt,
                                               OutT* __restrict__ C, int M, int N, int K,
                                               const float* __restrict__ mu,
                                               const float* __restrict__ rstd,
                                               const float* __restrict__ t1,
                                               const float* __restrict__ t2) {
  __shared__ __align__(16) unsigned short As[128 * 32];
  __shared__ __align__(16) unsigned short Bs[128 * 32];
  const int tid = threadIdx.x;
  const int wave = tid >> 6, lane = tid & 63;
  const int m0 = blockIdx.y * 128, n0 = blockIdx.x * 128;
  const int wr = (wave >> 1) * 64, wc = (wave & 1) * 64;
  const int st_row = lane >> 2;
  const int st_col = (((lane & 3) ^ ((st_row >> 1) & 3))) * 8;  // XOR swizzle
  const unsigned short* pA[2];
  const unsigned short* pB[2];
  unsigned short* lA[2];
  unsigned short* lB[2];
#pragma unroll
  for (int r = 0; r < 2; r++) {
    int q = wave * 2 + r;
    pA[r] = A + (size_t)(m0 + q * 16 + st_row) * K + st_col;
    pB[r] = Bt + (size_t)(n0 + q * 16 + st_row) * K + st_col;
    lA[r] = &As[q * 512];
    lB[r] = &Bs[q * 512];
  }
  const int frag_row = lane & 15;
  const int rk = (((lane >> 4) ^ ((frag_row >> 1) & 3))) * 8;
  f32x4 acc[4][4] = {};
  for (int k0 = 0; k0 < K; k0 += 32) {
#pragma unroll
    for (int r = 0; r < 2; r++) {
      gld_lds16(pA[r] + k0, lA[r]);
      gld_lds16(pB[r] + k0, lB[r]);
    }
    asm volatile("s_waitcnt vmcnt(0)" ::: "memory");
    __syncthreads();
    bf16x8 af[4], bfr[4];
#pragma unroll
    for (int i = 0; i < 4; i++)
      af[i] = *(const bf16x8*)&As[(wr + i * 16 + frag_row) * 32 + rk];
#pragma unroll
    for (int j = 0; j < 4; j++)
      bfr[j] = *(const bf16x8*)&Bs[(wc + j * 16 + frag_row) * 32 + rk];
#pragma unroll
    for (int i = 0; i < 4; i++)
#pragma unroll
      for (int j = 0; j < 4; j++)
        acc[i][j] = __builtin_amdgcn_mfma_f32_16x16x32_bf16(af[i], bfr[j], acc[i][j], 0, 0, 0);
    __syncthreads();
  }
  const int crow = (lane >> 4) * 4;
  const int ccol = lane & 15;
#pragma unroll
  for (int i = 0; i < 4; i++) {
#pragma unroll
    for (int j = 0; j < 4; j++) {
      int n = n0 + wc + j * 16 + ccol;
      if (n < N) {
        float c1 = FOLD ? t1[n] : 0.f;
        float c2 = FOLD ? t2[n] : 0.f;
#pragma unroll
        for (int r = 0; r < 4; r++) {
          int m = m0 + wr + i * 16 + crow + r;
          float v = acc[i][j][r];
          if (FOLD) v = rstd[m] * (v - mu[m] * c1) + c2;
          store_out(C, (size_t)m * N + n, v);
        }
      }
    }
  }
}

// ---- K2: dt = softplus(dt_raw + dt_bias)
__global__ void dt_kernel(const unsigned short* __restrict__ zxbcdt,
                          const float* __restrict__ dt_bias,
                          float* __restrict__ dtbuf) {
  int idx = blockIdx.x * 256 + threadIdx.x;
  if (idx >= kRows * kNH) return;
  int row = idx >> 5, h = idx & 31;
  float x = bu2f(zxbcdt[(size_t)row * kDProj + (kDProj - kNH) + h]) + dt_bias[h];
  dtbuf[idx] = (x > 15.f) ? x : log1pf(expf(x));
}

// ---- K3: causal depthwise conv (k=4) + SiLU, 8 rows x 4 cols per thread
__global__ void conv_silu_kernel(const unsigned short* __restrict__ zxbcdt,
                                 const float* __restrict__ conv_w,
                                 const float* __restrict__ conv_b,
                                 unsigned short* __restrict__ xbc_act) {
  int c4 = blockIdx.x * 256 + threadIdx.x;
  if (c4 >= kConvDim / 4) return;
  const int c = c4 * 4;
  const int r0 = blockIdx.y * 8;
  const int l0 = r0 & (kL - 1);
  float4 w[4];
  float bias[4];
#pragma unroll
  for (int q = 0; q < 4; q++) {
    w[q] = ((const float4*)conv_w)[c + q];
    bias[q] = conv_b[c + q];
  }
  float v[11][4];
#pragma unroll
  for (int i = 0; i < 11; i++) {
    int l = l0 - 3 + i;
    if (l >= 0) {
      ushort4 t = *(const ushort4*)&zxbcdt[(size_t)(r0 - 3 + i) * kDProj + kDI + c];
      v[i][0] = bu2f(t.x); v[i][1] = bu2f(t.y); v[i][2] = bu2f(t.z); v[i][3] = bu2f(t.w);
    } else {
      v[i][0] = v[i][1] = v[i][2] = v[i][3] = 0.f;
    }
  }
#pragma unroll
  for (int j = 0; j < 8; j++) {
    ushort4 o;
    unsigned short* op = (unsigned short*)&o;
#pragma unroll
    for (int q = 0; q < 4; q++) {
      float a = bias[q] + v[j][q] * w[q].x + v[j + 1][q] * w[q].y +
                v[j + 2][q] * w[q].z + v[j + 3][q] * w[q].w;
      op[q] = f2bu(a / (1.f + expf(-a)));
    }
    *(ushort4*)&xbc_act[(size_t)(r0 + j) * kConvDim + c] = o;
  }
}

// ---- K4: per-(b,chunk,head) end-of-chunk state via MFMA
__global__ __launch_bounds__(256) void chunk_state_kernel(
    const unsigned short* __restrict__ xbc_act,
    const float* __restrict__ dtbuf,
    const float* __restrict__ A_log,
    unsigned short* __restrict__ states,
    float* __restrict__ asum) {
  const int id = blockIdx.x;
  const int h = id & 31;
  const int c = (id >> 5) & (kNC - 1);
  const int b = id >> 11;
  const int tid = threadIdx.x;
  const int wave = tid >> 6, lane = tid & 63;
  __shared__ __align__(16) unsigned short sBT[kDS * kWS];
  __shared__ __align__(16) unsigned short sxd[kCS * kWS];
  __shared__ float s_dt[kCS];
  __shared__ float s_acum[kCS];
  const int l0 = b * kL + c * kCS;
  if (tid < kCS) s_dt[tid] = dtbuf[(size_t)(l0 + tid) * kNH + h];
  __syncthreads();
  if (tid == 0) {
    float A = -expf(A_log[h]);
    float run = 0.f;
    for (int s = 0; s < kCS; s++) { run += A * s_dt[s]; s_acum[s] = run; }
    asum[id] = run;
  }
  __syncthreads();
  const float total = s_acum[kCS - 1];
  for (int e = tid; e < kCS * kDS; e += 256) {
    int s = e >> 7, n = e & 127;
    sBT[n * kWS + s] = xbc_act[(size_t)(l0 + s) * kConvDim + kDI + n];
  }
  for (int e = tid; e < kCS * kHP; e += 256) {
    int s = e >> 6, p = e & 63;
    float xv = bu2f(xbc_act[(size_t)(l0 + s) * kConvDim + h * kHP + p]);
    sxd[p * kWS + s] = f2bu(xv * s_dt[s] * expf(total - s_acum[s]));
  }
  __syncthreads();
  const int arow = wave * 16 + (lane & 15);
  const int fk = (lane >> 4) * 8;
  f32x4 acc[8] = {};
#pragma unroll
  for (int kk = 0; kk < 2; kk++) {
    bf16x8 a = *(const bf16x8*)&sxd[arow * kWS + kk * 32 + fk];
#pragma unroll
    for (int j = 0; j < 8; j++) {
      bf16x8 bb = *(const bf16x8*)&sBT[(j * 16 + (lane & 15)) * kWS + kk * 32 + fk];
      acc[j] = __builtin_amdgcn_mfma_f32_16x16x32_bf16(a, bb, acc[j], 0, 0, 0);
    }
  }
  const int prow = wave * 16 + (lane >> 4) * 4;
  const int ncol = lane & 15;
  size_t base = (size_t)id * (kHP * kDS);
#pragma unroll
  for (int j = 0; j < 8; j++)
#pragma unroll
    for (int r = 0; r < 4; r++)
      states[base + (size_t)(prow + r) * kDS + j * 16 + ncol] = f2bu(acc[j][r]);
}

// ---- K5: sequential inter-chunk scan with software prefetch
__global__ void scan_kernel(unsigned short* __restrict__ states,
                            const float* __restrict__ asum) {
  const int blk = blockIdx.x;
  const int seg = blk & 7;
  const int bh = blk >> 3;
  const int h = bh & 31, b = bh >> 5;
  const int e4 = seg * 256 + threadIdx.x;
  const size_t cstride = (size_t)kNH * 2048;            // ushort4 units per chunk
  ushort4* p = (ushort4*)states + ((size_t)(b * kNC) * kNH + h) * 2048 + e4;
  const float* ap = asum + (b * kNC) * kNH + h;
  float c0 = 0.f, c1 = 0.f, c2 = 0.f, c3 = 0.f;
  ushort4 t = p[0];
  float dec = expf(ap[0]);
  for (int c = 0; c < kNC; c++) {
    ushort4 tn = t;
    float decn = dec;
    if (c + 1 < kNC) {                                  // prefetch next chunk
      tn = p[(size_t)(c + 1) * cstride];
      decn = expf(ap[(c + 1) * kNH]);
    }
    ushort4 o;
    o.x = f2bu(c0); o.y = f2bu(c1); o.z = f2bu(c2); o.w = f2bu(c3);
    p[(size_t)c * cstride] = o;
    c0 = c0 * dec + bu2f(t.x);
    c1 = c1 * dec + bu2f(t.y);
    c2 = c2 * dec + bu2f(t.z);
    c3 = c3 * dec + bu2f(t.w);
    t = tn; dec = decn;
  }
}

// ---- K6: intra-chunk Y, 4 heads/block (round-6 version: Sin staged via LDS)
__global__ __launch_bounds__(256) void y_kernel(
    const unsigned short* __restrict__ xbc_act,
    const unsigned short* __restrict__ zxbcdt,
    const unsigned short* __restrict__ states_in,
    const float* __restrict__ dtbuf,
    const float* __restrict__ A_log,
    unsigned short* __restrict__ ybuf,
    float* __restrict__ pS, float* __restrict__ pQ) {
  const int id = blockIdx.x;                 // (b*NC + c)*8 + hg
  const int hg = id & 7;
  const int c = (id >> 3) & (kNC - 1);
  const int b = id >> 9;
  const int tid = threadIdx.x;
  const int wave = tid >> 6, lane = tid & 63;
  __shared__ __align__(16) unsigned short sC[kCS * kTS];
  __shared__ __align__(16) unsigned short sB[kCS * kTS];
  __shared__ __align__(16) unsigned short sxd[kCS * kWS];
  __shared__ __align__(16) unsigned short sW[kCS * kWS];
  __shared__ float s_dt[4][kCS];
  __shared__ float s_acum[4][kCS];
  const int l0 = b * kL + c * kCS;
  {
    int hh = tid >> 6, s = tid & 63;
    s_dt[hh][s] = dtbuf[(size_t)(l0 + s) * kNH + hg * 4 + hh];
  }
  __syncthreads();
  if (tid < 4) {
    float A = -expf(A_log[hg * 4 + tid]);
    float run = 0.f;
    for (int s = 0; s < kCS; s++) { run += A * s_dt[tid][s]; s_acum[tid][s] = run; }
  }
  for (int e = tid; e < kCS * 16; e += 256) {
    int row = e >> 4, c8 = (e & 15) * 8;
    size_t rb = (size_t)(l0 + row) * kConvDim;
    *(ushort8*)&sB[row * kTS + c8] = *(const ushort8*)&xbc_act[rb + kDI + c8];
    *(ushort8*)&sC[row * kTS + c8] = *(const ushort8*)&xbc_act[rb + kDI + kDS + c8];
  }
  __syncthreads();
  const int arow = wave * 16 + (lane & 15);
  const int fk = (lane >> 4) * 8;
  // G[l][s] = C . B^T  (K=128) — head-independent, once per block
  f32x4 accG[4] = {};
#pragma unroll
  for (int kk = 0; kk < 4; kk++) {
    bf16x8 a = *(const bf16x8*)&sC[arow * kTS + kk * 32 + fk];
#pragma unroll
    for (int j = 0; j < 4; j++) {
      bf16x8 bb = *(const bf16x8*)&sB[(j * 16 + (lane & 15)) * kTS + kk * 32 + fk];
      accG[j] = __builtin_amdgcn_mfma_f32_16x16x32_bf16(a, bb, accG[j], 0, 0, 0);
    }
  }
  const int lrow = wave * 16 + (lane >> 4) * 4;
  const size_t sbase = (size_t)((b * kNC + c) * kNH) * (kHP * kDS);
  float rS[4] = {}, rQ[4] = {};
  for (int hh = 0; hh < 4; hh++) {
    const int h = hg * 4 + hh;
    __syncthreads();   // prior iteration (or G) done reading sB/sxd/sW
    // stage xd^T for this head
    for (int e = tid; e < kCS * kHP; e += 256) {
      int s = e >> 6, p = e & 63;
      float xv = bu2f(xbc_act[(size_t)(l0 + s) * kConvDim + h * kHP + p]);
      sxd[p * kWS + s] = f2bu(xv * s_dt[hh][s]);
    }
    // W = mask(G)*decay  (wave-local strip)
#pragma unroll
    for (int j = 0; j < 4; j++) {
      int scol = j * 16 + (lane & 15);
      float as = s_acum[hh][scol];
#pragma unroll
      for (int r = 0; r < 4; r++) {
        int l = lrow + r;
        float w = (scol <= l) ? accG[j][r] * expf(s_acum[hh][l] - as) : 0.f;
        sW[l * kWS + scol] = f2bu(w);
      }
    }
    // stage Sin[p][n] for this head into sB
    for (int e = tid; e < kCS * 16; e += 256) {
      int row = e >> 4, c8 = (e & 15) * 8;
      *(ushort8*)&sB[row * kTS + c8] =
          *(const ushort8*)&states_in[sbase + (size_t)h * (kHP * kDS) + row * kDS + c8];
    }
    __syncthreads();
    // Yd = W . xd^T  (K=64)
    f32x4 accY[4] = {};
#pragma unroll
    for (int kk = 0; kk < 2; kk++) {
      bf16x8 a = *(const bf16x8*)&sW[arow * kWS + kk * 32 + fk];
#pragma unroll
      for (int j = 0; j < 4; j++) {
        bf16x8 bb = *(const bf16x8*)&sxd[(j * 16 + (lane & 15)) * kWS + kk * 32 + fk];
        accY[j] = __builtin_amdgcn_mfma_f32_16x16x32_bf16(a, bb, accY[j], 0, 0, 0);
      }
    }
    // Yoff = C . Sin^T  (K=128)
    f32x4 accO[4] = {};
#pragma unroll
    for (int kk = 0; kk < 4; kk++) {
      bf16x8 a = *(const bf16x8*)&sC[arow * kTS + kk * 32 + fk];
#pragma unroll
      for (int j = 0; j < 4; j++) {
        bf16x8 bb = *(const bf16x8*)&sB[(j * 16 + (lane & 15)) * kTS + kk * 32 + fk];
        accO[j] = __builtin_amdgcn_mfma_f32_16x16x32_bf16(a, bb, accO[j], 0, 0, 0);
      }
    }
#pragma unroll
    for (int r = 0; r < 4; r++) {
      int l = lrow + r;
      float el = expf(s_acum[hh][l]);
      size_t zrow = (size_t)(l0 + l) * kDProj + h * kHP;
      size_t yrow = (size_t)(l0 + l) * kDI + h * kHP;
#pragma unroll
      for (int j = 0; j < 4; j++) {
        int p = j * 16 + (lane & 15);
        float yv = accY[j][r] + el * accO[j][r];
        float z = bu2f(zxbcdt[zrow + p]);
        yv *= z / (1.f + expf(-z));
        rS[r] += yv;
        rQ[r] += yv * yv;
        ybuf[yrow + p] = f2bu(yv);
      }
    }
  }
#pragma unroll
  for (int m = 1; m < 16; m <<= 1) {
#pragma unroll
    for (int r = 0; r < 4; r++) {
      rS[r] += __shfl_xor(rS[r], m);
      rQ[r] += __shfl_xor(rQ[r], m);
    }
  }
  if ((lane & 15) == 0) {
#pragma unroll
    for (int r = 0; r < 4; r++) {
      int row = l0 + lrow + r;
      pS[(size_t)row * 8 + hg] = rS[r];
      pQ[(size_t)row * 8 + hg] = rQ[r];
    }
  }
}

// ---- K7: finalize LN stats from per-block partials
__global__ void ln_reduce(const float* __restrict__ pS, const float* __restrict__ pQ,
                          float* __restrict__ mu, float* __restrict__ rstd) {
  int row = blockIdx.x * 256 + threadIdx.x;
  if (row >= kRows) return;
  float s = 0.f, q = 0.f;
#pragma unroll
  for (int i = 0; i < 8; i++) { s += pS[(size_t)row * 8 + i]; q += pQ[(size_t)row * 8 + i]; }
  float m = s / kDI;
  mu[row] = m;
  rstd[row] = rsqrtf(q / kDI - m * m + kEps);
}

}  // namespace

extern "C" void kernel_launch(void* const* d_in, const int* in_sizes, int n_in,
                              void* d_out, int out_size, void* d_ws, size_t ws_size,
                              hipStream_t stream) {
  const float* u       = (const float*)d_in[0];
  const float* W_in    = (const float*)d_in[1];
  const float* conv_w  = (const float*)d_in[2];
  const float* conv_b  = (const float*)d_in[3];
  const float* dt_bias = (const float*)d_in[4];
  const float* A_log   = (const float*)d_in[5];
  const float* norm_w  = (const float*)d_in[6];
  const float* norm_b  = (const float*)d_in[7];
  const float* W_out   = (const float*)d_in[8];
  float* out = (float*)d_out;

  char* ws = (char*)d_ws;
  size_t off = 0;
  auto alloc = [&](size_t bytes) {
    void* p = ws + off;
    off += (bytes + 255) & ~(size_t)255;
    return p;
  };
  unsigned short* zxbcdt = (unsigned short*)alloc((size_t)kRows * kDProj * 2);        // 71.8 MB
  unsigned short* xbc    = (unsigned short*)alloc((size_t)kRows * kConvDim * 2);      // 37.7 MB
  float* dtb             = (float*)alloc((size_t)kRows * kNH * 4);                    //  1.0 MB
  float* asum            = (float*)alloc((size_t)kB * kNC * kNH * 4);                 // 16 KB
  unsigned short* A1     = (unsigned short*)alloc((size_t)kRows * 1024 * 2);          // 16.8 MB
  unsigned short* Bt1    = (unsigned short*)alloc((size_t)kDProjP * 1024 * 2);        //  9.2 MB
  unsigned short* states = (unsigned short*)alloc((size_t)kB * kNC * kNH * kHP * kDS * 2); // 67.1 MB
  unsigned short* Bt2    = (unsigned short*)alloc((size_t)1024 * kDI * 2);            //  4.2 MB
  unsigned short* ybuf   = (unsigned short*)alloc((size_t)kRows * kDI * 2);           // 33.6 MB
  float* mu              = (float*)alloc((size_t)kRows * 4);
  float* rstd            = (float*)alloc((size_t)kRows * 4);
  float* t1              = (float*)alloc(1024 * 4);
  float* t2              = (float*)alloc(1024 * 4);
  float* pS              = (float*)alloc((size_t)kRows * 8 * 4);                      // 256 KB
  float* pQ              = (float*)alloc((size_t)kRows * 8 * 4);                      // 256 KB
  (void)ws_size; (void)in_sizes; (void)n_in; (void)out_size;

  cast_kernel<<<(kRows * 1024 / 4 + 255) / 256, 256, 0, stream>>>(
      (const float4*)u, (ushort4*)A1, kRows * 1024 / 4);
  transpose_cast<<<dim3(kDProjP / 32, 1024 / 32), 256, 0, stream>>>(
      W_in, Bt1, 1024, kDProj, nullptr);
  transpose_cast<<<dim3(1024 / 32, 2048 / 32), 256, 0, stream>>>(
      W_out, Bt2, 2048, 1024, norm_w);
  colsum_kernel<<<16, 256, 0, stream>>>(W_out, norm_w, norm_b, t1, t2);
  gemm_bt<unsigned short, false><<<dim3(kDProjP / 128, kRows / 128), 256, 0, stream>>>(
      A1, Bt1, zxbcdt, kRows, kDProj, 1024, nullptr, nullptr, nullptr, nullptr);
  dt_kernel<<<(kRows * kNH + 255) / 256, 256, 0, stream>>>(zxbcdt, dt_bias, dtb);
  conv_silu_kernel<<<dim3(3, kRows / 8), 256, 0, stream>>>(zxbcdt, conv_w, conv_b, xbc);
  chunk_state_kernel<<<kB * kNC * kNH, 256, 0, stream>>>(xbc, dtb, A_log, states, asum);
  scan_kernel<<<kB * kNH * 8, 256, 0, stream>>>(states, asum);
  y_kernel<<<kB * kNC * 8, 256, 0, stream>>>(xbc, zxbcdt, states, dtb, A_log, ybuf, pS, pQ);
  ln_reduce<<<kRows / 256, 256, 0, stream>>>(pS, pQ, mu, rstd);
  gemm_bt<float, true><<<dim3(1024 / 128, kRows / 128), 256, 0, stream>>>(
      ybuf, Bt2, out, kRows, 1024, 2048, mu, rstd, t1, t2);
}